// Round 1
// baseline (2044.502 us; speedup 1.0000x reference)
//
#include <hip/hip_runtime.h>

#define N_NODES 50000
#define N_EDGES 800000
#define N_RELS 65
#define DIM 64
#define N_GRAPHS 512
#define EPW 200  // edges per wave in edge kernel; 800000/200 = 4000 waves

// ---------------- counting sort of edges by relation ----------------

__global__ void hist_kernel(const int* __restrict__ et, int* __restrict__ cnt) {
    __shared__ int lh[N_RELS];
    int t = threadIdx.x;
    if (t < N_RELS) lh[t] = 0;
    __syncthreads();
    int i = blockIdx.x * 256 + t;
    if (i < N_EDGES) atomicAdd(&lh[et[i]], 1);
    __syncthreads();
    if (t < N_RELS) { int v = lh[t]; if (v) atomicAdd(&cnt[t], v); }
}

__global__ void prefix_kernel(const int* __restrict__ cnt, int* __restrict__ cursor) {
    if (threadIdx.x == 0 && blockIdx.x == 0) {
        int s = 0;
        for (int r = 0; r < N_RELS; ++r) { cursor[r] = s; s += cnt[r]; }
    }
}

__global__ void scatter_kernel(const int* __restrict__ et, const int* __restrict__ src,
                               const int* __restrict__ dst, int* __restrict__ cursor,
                               int* __restrict__ et_s, int* __restrict__ src_s,
                               int* __restrict__ dst_s) {
    int i = blockIdx.x * 256 + threadIdx.x;
    if (i < N_EDGES) {
        int r = et[i];
        int p = atomicAdd(&cursor[r], 1);
        et_s[p] = r;
        src_s[p] = src[i];
        dst_s[p] = dst[i];
    }
}

// ---------------- RGCN edge message + scatter-add ----------------
// One wave per EPW contiguous sorted edges. W[r] column k lives in lane k's
// VGPRs (wcol[64]); reloaded only on relation change (sorted -> rare).
// src/dst/et made wave-uniform via readfirstlane so the h-row becomes
// scalar (SGPR) loads and the inner loop is 64 v_fmac with SGPR operand.

__global__ __launch_bounds__(256) void edge_kernel(
    const float* __restrict__ h, const float* __restrict__ W,
    const int* __restrict__ et_s, const int* __restrict__ src_s,
    const int* __restrict__ dst_s, float* __restrict__ agg) {
    int wave = __builtin_amdgcn_readfirstlane(blockIdx.x * 4 + (threadIdx.x >> 6));
    int lane = threadIdx.x & 63;
    int e0 = wave * EPW;
    if (e0 >= N_EDGES) return;
    int e1 = e0 + EPW;
    if (e1 > N_EDGES) e1 = N_EDGES;

    float wcol[DIM];
    int cur_r = -1;
    for (int e = e0; e < e1; ++e) {
        int r = __builtin_amdgcn_readfirstlane(et_s[e]);
        if (r != cur_r) {
            cur_r = r;
            const float* Wr = W + (size_t)r * (DIM * DIM);
            #pragma unroll
            for (int d = 0; d < DIM; ++d) wcol[d] = Wr[d * DIM + lane];
        }
        int s = __builtin_amdgcn_readfirstlane(src_s[e]);
        int t = __builtin_amdgcn_readfirstlane(dst_s[e]);
        const float* __restrict__ hrow = h + (size_t)s * DIM;
        float acc = 0.f;
        #pragma unroll
        for (int d = 0; d < DIM; ++d) acc += hrow[d] * wcol[d];
        atomicAdd(&agg[(size_t)t * DIM + lane], acc);
    }
}

__global__ void bias_relu_kernel(float* __restrict__ h, const float* __restrict__ b) {
    int i = blockIdx.x * 256 + threadIdx.x;
    if (i < N_NODES * DIM) {
        float v = h[i] + b[i & 63];
        h[i] = v > 0.f ? v : 0.f;
    }
}

// ---------------- graph sum-pool ----------------

__global__ void pool_kernel(const float* __restrict__ h, const int* __restrict__ gid,
                            float* __restrict__ g) {
    int i = blockIdx.x * 256 + threadIdx.x;
    if (i < N_NODES * DIM) {
        int n = i >> 6;
        atomicAdd(&g[(size_t)gid[n] * DIM + (i & 63)], h[i]);
    }
}

// ---------------- fused FC x3 + prediction head ----------------
// One wave per graph; lane k holds g[graph][k]; shfl-broadcast matvec.

__global__ __launch_bounds__(256) void fc_kernel(
    const float* __restrict__ g,
    const float* __restrict__ W1, const float* __restrict__ b1,
    const float* __restrict__ W2, const float* __restrict__ b2,
    const float* __restrict__ W3, const float* __restrict__ b3,
    const float* __restrict__ pW, const float* __restrict__ pb,
    float* __restrict__ out) {
    int wave = __builtin_amdgcn_readfirstlane(blockIdx.x * 4 + (threadIdx.x >> 6));
    int lane = threadIdx.x & 63;
    if (wave >= N_GRAPHS) return;

    float v = g[(size_t)wave * DIM + lane];

    const float* Ws[3] = {W1, W2, W3};
    const float* bs[3] = {b1, b2, b3};
    for (int l = 0; l < 3; ++l) {
        float acc = bs[l][lane];
        const float* __restrict__ Wl = Ws[l];
        #pragma unroll
        for (int d = 0; d < DIM; ++d)
            acc += __shfl(v, d) * Wl[d * DIM + lane];
        v = acc > 0.f ? acc : 0.f;
    }

    float p0 = v * pW[lane * 2 + 0];
    float p1 = v * pW[lane * 2 + 1];
    #pragma unroll
    for (int off = 32; off > 0; off >>= 1) {
        p0 += __shfl_down(p0, off);
        p1 += __shfl_down(p1, off);
    }
    if (lane == 0) {
        out[wave * 2 + 0] = p0 + pb[0];
        out[wave * 2 + 1] = p1 + pb[1];
    }
}

// ---------------- launch ----------------

extern "C" void kernel_launch(void* const* d_in, const int* in_sizes, int n_in,
                              void* d_out, int out_size, void* d_ws, size_t ws_size,
                              hipStream_t stream) {
    const float* node_feats = (const float*)d_in[0];
    const int*   etypes     = (const int*)d_in[1];
    const int*   src        = (const int*)d_in[2];
    const int*   dst        = (const int*)d_in[3];
    const int*   graph_ids  = (const int*)d_in[4];
    const float* W1 = (const float*)d_in[5];
    const float* b1 = (const float*)d_in[6];
    const float* W2 = (const float*)d_in[7];
    const float* b2 = (const float*)d_in[8];
    const float* W3 = (const float*)d_in[9];
    const float* b3 = (const float*)d_in[10];
    const float* fcW1 = (const float*)d_in[11];
    const float* fcb1 = (const float*)d_in[12];
    const float* fcW2 = (const float*)d_in[13];
    const float* fcb2 = (const float*)d_in[14];
    const float* fcW3 = (const float*)d_in[15];
    const float* fcb3 = (const float*)d_in[16];
    const float* pW = (const float*)d_in[17];
    const float* pb = (const float*)d_in[18];
    float* out = (float*)d_out;

    // workspace carve-up (256B aligned)
    char* p = (char*)d_ws;
    auto alloc = [&](size_t bytes) -> void* {
        void* r = (void*)p;
        p += (bytes + 255) & ~(size_t)255;
        return r;
    };
    int* cnt    = (int*)alloc(N_RELS * sizeof(int));
    int* cursor = (int*)alloc(N_RELS * sizeof(int));
    int* et_s   = (int*)alloc((size_t)N_EDGES * sizeof(int));
    int* src_s  = (int*)alloc((size_t)N_EDGES * sizeof(int));
    int* dst_s  = (int*)alloc((size_t)N_EDGES * sizeof(int));
    float* hA   = (float*)alloc((size_t)N_NODES * DIM * sizeof(float));
    float* hB   = (float*)alloc((size_t)N_NODES * DIM * sizeof(float));
    float* g    = (float*)alloc((size_t)N_GRAPHS * DIM * sizeof(float));

    const int EBLK = (N_EDGES + 255) / 256;        // 3125
    const int NBLK = (N_NODES * DIM + 255) / 256;  // 12500
    const int EDGE_BLOCKS = (N_EDGES / EPW + 3) / 4; // 4000 waves / 4 per block

    // sort edges by relation
    hipMemsetAsync(cnt, 0, N_RELS * sizeof(int), stream);
    hist_kernel<<<EBLK, 256, 0, stream>>>(etypes, cnt);
    prefix_kernel<<<1, 64, 0, stream>>>(cnt, cursor);
    scatter_kernel<<<EBLK, 256, 0, stream>>>(etypes, src, dst, cursor, et_s, src_s, dst_s);

    // layer 1: node_feats -> hA
    hipMemsetAsync(hA, 0, (size_t)N_NODES * DIM * sizeof(float), stream);
    edge_kernel<<<EDGE_BLOCKS, 256, 0, stream>>>(node_feats, W1, et_s, src_s, dst_s, hA);
    bias_relu_kernel<<<NBLK, 256, 0, stream>>>(hA, b1);

    // layer 2: hA -> hB
    hipMemsetAsync(hB, 0, (size_t)N_NODES * DIM * sizeof(float), stream);
    edge_kernel<<<EDGE_BLOCKS, 256, 0, stream>>>(hA, W2, et_s, src_s, dst_s, hB);
    bias_relu_kernel<<<NBLK, 256, 0, stream>>>(hB, b2);

    // layer 3: hB -> hA
    hipMemsetAsync(hA, 0, (size_t)N_NODES * DIM * sizeof(float), stream);
    edge_kernel<<<EDGE_BLOCKS, 256, 0, stream>>>(hB, W3, et_s, src_s, dst_s, hA);
    bias_relu_kernel<<<NBLK, 256, 0, stream>>>(hA, b3);

    // pool + FC head
    hipMemsetAsync(g, 0, (size_t)N_GRAPHS * DIM * sizeof(float), stream);
    pool_kernel<<<NBLK, 256, 0, stream>>>(hA, graph_ids, g);
    fc_kernel<<<(N_GRAPHS + 3) / 4, 256, 0, stream>>>(g, fcW1, fcb1, fcW2, fcb2,
                                                      fcW3, fcb3, pW, pb, out);
}

// Round 2
// 844.550 us; speedup vs baseline: 2.4208x; 2.4208x over previous
//
#include <hip/hip_runtime.h>

#define N_NODES 50000
#define N_EDGES 800000
#define N_RELS 65
#define DIM 64
#define N_GRAPHS 512
#define EPW 200  // edges per wave in edge kernel; 800000/200 = 4000 waves

#define SORT_BLOCKS 256
#define CHUNK ((N_EDGES + SORT_BLOCKS - 1) / SORT_BLOCKS)  // 3125

// ---------------- two-pass block-stable counting sort by relation ----------------

// Pass 1: per-block histogram (LDS only, no global atomics)
__global__ __launch_bounds__(256) void hist2_kernel(const int* __restrict__ et,
                                                    int* __restrict__ blk_hist) {
    __shared__ int lh[N_RELS];
    int t = threadIdx.x;
    int b = blockIdx.x;
    if (t < N_RELS) lh[t] = 0;
    __syncthreads();
    int lo = b * CHUNK;
    int hi = lo + CHUNK; if (hi > N_EDGES) hi = N_EDGES;
    for (int i = lo + t; i < hi; i += 256) atomicAdd(&lh[et[i]], 1);
    __syncthreads();
    if (t < N_RELS) blk_hist[b * N_RELS + t] = lh[t];
}

// Pass 2: per-relation column scan over blocks + relation base offsets.
// One block, 128 threads; thread r (r<65) owns relation r's column.
__global__ __launch_bounds__(128) void scan_kernel(const int* __restrict__ blk_hist,
                                                   int* __restrict__ blk_off) {
    __shared__ int total[N_RELS];
    __shared__ int rel_base[N_RELS];
    int r = threadIdx.x;
    if (r < N_RELS) {
        int run = 0;
        for (int b = 0; b < SORT_BLOCKS; ++b) {
            int idx = b * N_RELS + r;
            int v = blk_hist[idx];
            blk_off[idx] = run;
            run += v;
        }
        total[r] = run;
    }
    __syncthreads();
    if (r == 0) {
        int s = 0;
        for (int q = 0; q < N_RELS; ++q) { rel_base[q] = s; s += total[q]; }
    }
    __syncthreads();
    if (r < N_RELS) {
        int base = rel_base[r];
        for (int b = 0; b < SORT_BLOCKS; ++b) blk_off[b * N_RELS + r] += base;
    }
}

// Pass 3: scatter using LDS cursors seeded from blk_off — no global atomics,
// writes land in <=65 contiguous segments per block.
__global__ __launch_bounds__(256) void scatter2_kernel(
    const int* __restrict__ et, const int* __restrict__ src,
    const int* __restrict__ dst, const int* __restrict__ blk_off,
    int* __restrict__ et_s, int* __restrict__ src_s, int* __restrict__ dst_s) {
    __shared__ int cur[N_RELS];
    int t = threadIdx.x;
    int b = blockIdx.x;
    if (t < N_RELS) cur[t] = blk_off[b * N_RELS + t];
    __syncthreads();
    int lo = b * CHUNK;
    int hi = lo + CHUNK; if (hi > N_EDGES) hi = N_EDGES;
    for (int i = lo + t; i < hi; i += 256) {
        int r = et[i];
        int p = atomicAdd(&cur[r], 1);
        et_s[p] = r;
        src_s[p] = src[i];
        dst_s[p] = dst[i];
    }
}

// ---------------- RGCN edge message + scatter-add ----------------
// One wave per EPW contiguous sorted edges. W[r] column k lives in lane k's
// VGPRs (wcol[64]); reloaded only on relation change (sorted -> rare).
// src/dst/et made wave-uniform via readfirstlane so the h-row becomes
// scalar (SGPR) loads and the inner loop is 64 v_fmac with SGPR operand.

__global__ __launch_bounds__(256) void edge_kernel(
    const float* __restrict__ h, const float* __restrict__ W,
    const int* __restrict__ et_s, const int* __restrict__ src_s,
    const int* __restrict__ dst_s, float* __restrict__ agg) {
    int wave = __builtin_amdgcn_readfirstlane(blockIdx.x * 4 + (threadIdx.x >> 6));
    int lane = threadIdx.x & 63;
    int e0 = wave * EPW;
    if (e0 >= N_EDGES) return;
    int e1 = e0 + EPW;
    if (e1 > N_EDGES) e1 = N_EDGES;

    float wcol[DIM];
    int cur_r = -1;
    for (int e = e0; e < e1; ++e) {
        int r = __builtin_amdgcn_readfirstlane(et_s[e]);
        if (r != cur_r) {
            cur_r = r;
            const float* Wr = W + (size_t)r * (DIM * DIM);
            #pragma unroll
            for (int d = 0; d < DIM; ++d) wcol[d] = Wr[d * DIM + lane];
        }
        int s = __builtin_amdgcn_readfirstlane(src_s[e]);
        int t = __builtin_amdgcn_readfirstlane(dst_s[e]);
        const float* __restrict__ hrow = h + (size_t)s * DIM;
        float acc = 0.f;
        #pragma unroll
        for (int d = 0; d < DIM; ++d) acc += hrow[d] * wcol[d];
        atomicAdd(&agg[(size_t)t * DIM + lane], acc);
    }
}

__global__ void bias_relu_kernel(float* __restrict__ h, const float* __restrict__ b) {
    int i = blockIdx.x * 256 + threadIdx.x;
    if (i < N_NODES * DIM) {
        float v = h[i] + b[i & 63];
        h[i] = v > 0.f ? v : 0.f;
    }
}

// ---------------- graph sum-pool ----------------

__global__ void pool_kernel(const float* __restrict__ h, const int* __restrict__ gid,
                            float* __restrict__ g) {
    int i = blockIdx.x * 256 + threadIdx.x;
    if (i < N_NODES * DIM) {
        int n = i >> 6;
        atomicAdd(&g[(size_t)gid[n] * DIM + (i & 63)], h[i]);
    }
}

// ---------------- fused FC x3 + prediction head ----------------
// One wave per graph; lane k holds g[graph][k]; shfl-broadcast matvec.

__global__ __launch_bounds__(256) void fc_kernel(
    const float* __restrict__ g,
    const float* __restrict__ W1, const float* __restrict__ b1,
    const float* __restrict__ W2, const float* __restrict__ b2,
    const float* __restrict__ W3, const float* __restrict__ b3,
    const float* __restrict__ pW, const float* __restrict__ pb,
    float* __restrict__ out) {
    int wave = __builtin_amdgcn_readfirstlane(blockIdx.x * 4 + (threadIdx.x >> 6));
    int lane = threadIdx.x & 63;
    if (wave >= N_GRAPHS) return;

    float v = g[(size_t)wave * DIM + lane];

    const float* Ws[3] = {W1, W2, W3};
    const float* bs[3] = {b1, b2, b3};
    for (int l = 0; l < 3; ++l) {
        float acc = bs[l][lane];
        const float* __restrict__ Wl = Ws[l];
        #pragma unroll
        for (int d = 0; d < DIM; ++d)
            acc += __shfl(v, d) * Wl[d * DIM + lane];
        v = acc > 0.f ? acc : 0.f;
    }

    float p0 = v * pW[lane * 2 + 0];
    float p1 = v * pW[lane * 2 + 1];
    #pragma unroll
    for (int off = 32; off > 0; off >>= 1) {
        p0 += __shfl_down(p0, off);
        p1 += __shfl_down(p1, off);
    }
    if (lane == 0) {
        out[wave * 2 + 0] = p0 + pb[0];
        out[wave * 2 + 1] = p1 + pb[1];
    }
}

// ---------------- launch ----------------

extern "C" void kernel_launch(void* const* d_in, const int* in_sizes, int n_in,
                              void* d_out, int out_size, void* d_ws, size_t ws_size,
                              hipStream_t stream) {
    const float* node_feats = (const float*)d_in[0];
    const int*   etypes     = (const int*)d_in[1];
    const int*   src        = (const int*)d_in[2];
    const int*   dst        = (const int*)d_in[3];
    const int*   graph_ids  = (const int*)d_in[4];
    const float* W1 = (const float*)d_in[5];
    const float* b1 = (const float*)d_in[6];
    const float* W2 = (const float*)d_in[7];
    const float* b2 = (const float*)d_in[8];
    const float* W3 = (const float*)d_in[9];
    const float* b3 = (const float*)d_in[10];
    const float* fcW1 = (const float*)d_in[11];
    const float* fcb1 = (const float*)d_in[12];
    const float* fcW2 = (const float*)d_in[13];
    const float* fcb2 = (const float*)d_in[14];
    const float* fcW3 = (const float*)d_in[15];
    const float* fcb3 = (const float*)d_in[16];
    const float* pW = (const float*)d_in[17];
    const float* pb = (const float*)d_in[18];
    float* out = (float*)d_out;

    // workspace carve-up (256B aligned)
    char* p = (char*)d_ws;
    auto alloc = [&](size_t bytes) -> void* {
        void* r = (void*)p;
        p += (bytes + 255) & ~(size_t)255;
        return r;
    };
    int* blk_hist = (int*)alloc((size_t)SORT_BLOCKS * N_RELS * sizeof(int));
    int* blk_off  = (int*)alloc((size_t)SORT_BLOCKS * N_RELS * sizeof(int));
    int* et_s   = (int*)alloc((size_t)N_EDGES * sizeof(int));
    int* src_s  = (int*)alloc((size_t)N_EDGES * sizeof(int));
    int* dst_s  = (int*)alloc((size_t)N_EDGES * sizeof(int));
    float* hA   = (float*)alloc((size_t)N_NODES * DIM * sizeof(float));
    float* hB   = (float*)alloc((size_t)N_NODES * DIM * sizeof(float));
    float* g    = (float*)alloc((size_t)N_GRAPHS * DIM * sizeof(float));

    const int NBLK = (N_NODES * DIM + 255) / 256;  // 12500
    const int EDGE_BLOCKS = (N_EDGES / EPW + 3) / 4; // 4000 waves / 4 per block

    // sort edges by relation (block-stable counting sort, no global atomics)
    hist2_kernel<<<SORT_BLOCKS, 256, 0, stream>>>(etypes, blk_hist);
    scan_kernel<<<1, 128, 0, stream>>>(blk_hist, blk_off);
    scatter2_kernel<<<SORT_BLOCKS, 256, 0, stream>>>(etypes, src, dst, blk_off,
                                                     et_s, src_s, dst_s);

    // layer 1: node_feats -> hA
    hipMemsetAsync(hA, 0, (size_t)N_NODES * DIM * sizeof(float), stream);
    edge_kernel<<<EDGE_BLOCKS, 256, 0, stream>>>(node_feats, W1, et_s, src_s, dst_s, hA);
    bias_relu_kernel<<<NBLK, 256, 0, stream>>>(hA, b1);

    // layer 2: hA -> hB
    hipMemsetAsync(hB, 0, (size_t)N_NODES * DIM * sizeof(float), stream);
    edge_kernel<<<EDGE_BLOCKS, 256, 0, stream>>>(hA, W2, et_s, src_s, dst_s, hB);
    bias_relu_kernel<<<NBLK, 256, 0, stream>>>(hB, b2);

    // layer 3: hB -> hA
    hipMemsetAsync(hA, 0, (size_t)N_NODES * DIM * sizeof(float), stream);
    edge_kernel<<<EDGE_BLOCKS, 256, 0, stream>>>(hB, W3, et_s, src_s, dst_s, hA);
    bias_relu_kernel<<<NBLK, 256, 0, stream>>>(hA, b3);

    // pool + FC head
    hipMemsetAsync(g, 0, (size_t)N_GRAPHS * DIM * sizeof(float), stream);
    pool_kernel<<<NBLK, 256, 0, stream>>>(hA, graph_ids, g);
    fc_kernel<<<(N_GRAPHS + 3) / 4, 256, 0, stream>>>(g, fcW1, fcb1, fcW2, fcb2,
                                                      fcW3, fcb3, pW, pb, out);
}